// Round 2
// baseline (4184.497 us; speedup 1.0000x reference)
//
#include <hip/hip_runtime.h>
#include <hip/hip_bf16.h>

#define SEQ   2048
#define DIM   300
#define UU    150
#define G4    600   // 4*U
#define H1    300
#define NSYN  4

static __device__ __forceinline__ float sigm(float x) { return 1.0f / (1.0f + __expf(-x)); }
static __device__ __forceinline__ float tanh_fast(float x) { return 1.0f - 2.0f / (1.0f + __expf(2.0f * x)); }

// ---------------------------------------------------------------------------
// Kernel A: emb = embedding[sentence];  Xpre_dir = emb @ Wk_dir + b_dir
// grid (SEQ/8, 2), block 640
// ---------------------------------------------------------------------------
__global__ void xpre_kernel(const int* __restrict__ sentence,
                            const float* __restrict__ emb_mat,
                            const float* __restrict__ Wk_f,
                            const float* __restrict__ b_f,
                            const float* __restrict__ Wk_b,
                            const float* __restrict__ b_b,
                            float* __restrict__ Xf, float* __restrict__ Xb)
{
    const int dir = blockIdx.y;
    const float* Wk = dir ? Wk_b : Wk_f;
    const float* bb = dir ? b_b : b_f;
    float* X = dir ? Xb : Xf;

    const int s0  = blockIdx.x * 8;
    const int tid = threadIdx.x;

    __shared__ int   sids[8];
    __shared__ float embs[8][DIM];

    if (tid < 8) sids[tid] = sentence[s0 + tid];
    __syncthreads();
    for (int e = tid; e < 8 * DIM; e += 640) {
        int r = e / DIM, d = e - r * DIM;
        embs[r][d] = emb_mat[(long)sids[r] * DIM + d];
    }
    __syncthreads();

    if (tid < G4) {
        float acc[8];
        float bv = bb[tid];
        #pragma unroll
        for (int r = 0; r < 8; ++r) acc[r] = bv;
        for (int k = 0; k < DIM; ++k) {
            float wv = Wk[k * G4 + tid];
            #pragma unroll
            for (int r = 0; r < 8; ++r) acc[r] = fmaf(embs[r][k], wv, acc[r]);
        }
        #pragma unroll
        for (int r = 0; r < 8; ++r) X[(long)(s0 + r) * G4 + tid] = acc[r];
    }
}

// ---------------------------------------------------------------------------
// Kernel B: sequential LSTM scan, one block per direction.
// 640 threads; threads 0..599 each own one Wr column (150 fp32 in registers).
// h lives in LDS; 2 barriers per step.
// ---------------------------------------------------------------------------
__global__ __launch_bounds__(640, 3) void lstm_scan_kernel(
    const float* __restrict__ Xf, const float* __restrict__ Xb,
    const float* __restrict__ Wr_f, const float* __restrict__ Wr_b,
    float* __restrict__ hidden)
{
    const int dir = blockIdx.x;
    const float* X = dir ? Xb : Xf;
    const float* Wr = dir ? Wr_b : Wr_f;
    const int tid = threadIdx.x;

    __shared__ float hs[UU];
    __shared__ float zs[G4];

    float w[UU];
    if (tid < G4) {
        #pragma unroll
        for (int u = 0; u < UU; ++u) w[u] = Wr[u * G4 + tid];
    }
    if (tid < UU) hs[tid] = 0.0f;
    float c = 0.0f;

    int t = dir ? (SEQ - 1) : 0;
    const int dt = dir ? -1 : 1;
    float xcur = (tid < G4) ? X[(long)t * G4 + tid] : 0.0f;
    __syncthreads();

    for (int step = 0; step < SEQ; ++step) {
        const int tn = t + dt;
        // prefetch next step's pre-activation (hidden under the dot chain)
        float xnext = (tid < G4 && step < SEQ - 1) ? X[(long)tn * G4 + tid] : 0.0f;

        if (tid < G4) {
            float a0 = xcur, a1 = 0.0f;
            #pragma unroll
            for (int u = 0; u < UU; u += 2) {
                a0 = fmaf(hs[u],     w[u],     a0);
                a1 = fmaf(hs[u + 1], w[u + 1], a1);
            }
            zs[tid] = a0 + a1;
        }
        __syncthreads();

        if (tid < UU) {
            float zi = zs[tid], zf = zs[UU + tid], zg = zs[2 * UU + tid], zo = zs[3 * UU + tid];
            float ig = sigm(zi);
            float fg = sigm(zf);
            float gg = tanh_fast(zg);
            float og = sigm(zo);
            c = fg * c + ig * gg;
            float hv = og * tanh_fast(c);
            hs[tid] = hv;
            hidden[(long)t * H1 + dir * UU + tid] = hv;
        }
        __syncthreads();

        xcur = xnext;
        t = tn;
    }
}

// ---------------------------------------------------------------------------
// Kernel C: out = hidden @ W1 + b1   [2048,300]x[300,300]
// grid SEQ/8, block 320
// ---------------------------------------------------------------------------
__global__ void w1_kernel(const float* __restrict__ hidden,
                          const float* __restrict__ W1,
                          const float* __restrict__ b1,
                          float* __restrict__ outm)
{
    const int s0  = blockIdx.x * 8;
    const int tid = threadIdx.x;
    __shared__ float hl[8][H1];
    for (int e = tid; e < 8 * H1; e += 320)
        hl[e / H1][e - (e / H1) * H1] = hidden[(long)s0 * H1 + e];
    __syncthreads();

    if (tid < H1) {
        float acc[8];
        float bv = b1[tid];
        #pragma unroll
        for (int r = 0; r < 8; ++r) acc[r] = bv;
        for (int k = 0; k < H1; ++k) {
            float wv = W1[k * H1 + tid];
            #pragma unroll
            for (int r = 0; r < 8; ++r) acc[r] = fmaf(hl[r][k], wv, acc[r]);
        }
        #pragma unroll
        for (int r = 0; r < 8; ++r) outm[(long)(s0 + r) * H1 + tid] = acc[r];
    }
}

// ---------------------------------------------------------------------------
// Block reductions for 320-thread blocks (5 waves)
// ---------------------------------------------------------------------------
static __device__ __forceinline__ float4 blockReduce4(float4 v, float* red, int tid)
{
    #pragma unroll
    for (int off = 32; off > 0; off >>= 1) {
        v.x += __shfl_down(v.x, off);
        v.y += __shfl_down(v.y, off);
        v.z += __shfl_down(v.z, off);
        v.w += __shfl_down(v.w, off);
    }
    __syncthreads();
    if ((tid & 63) == 0) {
        int wv = tid >> 6;
        red[wv * 4 + 0] = v.x; red[wv * 4 + 1] = v.y;
        red[wv * 4 + 2] = v.z; red[wv * 4 + 3] = v.w;
    }
    __syncthreads();
    float4 r;
    r.x = red[0]; r.y = red[1]; r.z = red[2]; r.w = red[3];
    #pragma unroll
    for (int wv = 1; wv < 5; ++wv) {
        r.x += red[wv * 4 + 0]; r.y += red[wv * 4 + 1];
        r.z += red[wv * 4 + 2]; r.w += red[wv * 4 + 3];
    }
    return r;
}

static __device__ __forceinline__ float blockReduce1(float v, float* red, int tid)
{
    #pragma unroll
    for (int off = 32; off > 0; off >>= 1) v += __shfl_down(v, off);
    __syncthreads();
    if ((tid & 63) == 0) red[tid >> 6] = v;
    __syncthreads();
    return red[0] + red[1] + red[2] + red[3] + red[4];
}

// ---------------------------------------------------------------------------
// Kernel D: per-position synonym attention; writes whh[s][d] = c2[s]*h_hat[s][d]
// grid SEQ, block 320
// ---------------------------------------------------------------------------
__global__ void attn_kernel(const int* __restrict__ sentence,
                            const int* __restrict__ syn_idx,
                            const float* __restrict__ emb_mat,
                            const float* __restrict__ outm,
                            const float* __restrict__ hidden,
                            const float* __restrict__ W2,
                            const float* __restrict__ b2,
                            float* __restrict__ whh)
{
    const int s   = blockIdx.x;
    const int t   = s ? (s - 1) : 0;
    const int tid = threadIdx.x;
    __shared__ float red[20];

    const int sent = sentence[s];
    const long i0 = (long)syn_idx[sent * NSYN + 0] * DIM;
    const long i1 = (long)syn_idx[sent * NSYN + 1] * DIM;
    const long i2 = (long)syn_idx[sent * NSYN + 2] * DIM;
    const long i3 = (long)syn_idx[sent * NSYN + 3] * DIM;

    float se0 = 0.f, se1 = 0.f, se2 = 0.f, se3 = 0.f, od = 0.f, hd = 0.f;
    if (tid < DIM) {
        se0 = emb_mat[i0 + tid];
        se1 = emb_mat[i1 + tid];
        se2 = emb_mat[i2 + tid];
        se3 = emb_mat[i3 + tid];
        od  = outm[(long)t * H1 + tid];
        hd  = hidden[(long)t * H1 + tid];
    }

    float4 dots = blockReduce4(make_float4(se0 * od, se1 * od, se2 * od, se3 * od), red, tid);
    float c0 = __expf(dots.x), c1 = __expf(dots.y), c2c = __expf(dots.z), c3 = __expf(dots.w);

    float hh = fmaf(c0, se0, fmaf(c1, se1, fmaf(c2c, se2, fmaf(c3, se3, hd))));

    float w2v = (tid < DIM) ? W2[tid] : 0.f;
    float dot2 = blockReduce1(hh * w2v, red, tid);
    float cc = __expf(tanh_fast(dot2 + b2[0]));

    if (tid < DIM) whh[(long)s * H1 + tid] = cc * hh;
}

// ---------------------------------------------------------------------------
// Kernel E: H[d] = sum_s whh[s][d]      grid H1, block 256
// ---------------------------------------------------------------------------
__global__ void hred_kernel(const float* __restrict__ whh, float* __restrict__ H)
{
    const int d   = blockIdx.x;
    const int tid = threadIdx.x;
    float acc = 0.f;
    for (int s = tid; s < SEQ; s += 256) acc += whh[(long)s * H1 + d];
    #pragma unroll
    for (int off = 32; off > 0; off >>= 1) acc += __shfl_down(acc, off);
    __shared__ float red[4];
    if ((tid & 63) == 0) red[tid >> 6] = acc;
    __syncthreads();
    if (tid == 0) H[d] = red[0] + red[1] + red[2] + red[3];
}

// ---------------------------------------------------------------------------
// Kernel F: logits. out[0..7]=H@We+be, out[8]=H@Ws+bs.  1 block, 64 threads
// ---------------------------------------------------------------------------
__global__ void logits_kernel(const float* __restrict__ H,
                              const float* __restrict__ We,
                              const float* __restrict__ be,
                              const float* __restrict__ Ws,
                              const float* __restrict__ bs,
                              float* __restrict__ outp)
{
    const int e = threadIdx.x;
    if (e < 9) {
        float acc = (e < 8) ? be[e] : bs[0];
        for (int d = 0; d < H1; ++d) {
            float wv = (e < 8) ? We[d * 8 + e] : Ws[d];
            acc = fmaf(H[d], wv, acc);
        }
        outp[e] = acc;
    }
}

// ---------------------------------------------------------------------------
extern "C" void kernel_launch(void* const* d_in, const int* in_sizes, int n_in,
                              void* d_out, int out_size, void* d_ws, size_t ws_size,
                              hipStream_t stream)
{
    const int* sentence   = (const int*)d_in[0];
    const int* syn_idx    = (const int*)d_in[1];
    const float* emb      = (const float*)d_in[2];
    const float* Wk_f     = (const float*)d_in[3];
    const float* Wr_f     = (const float*)d_in[4];
    const float* b_f      = (const float*)d_in[5];
    const float* Wk_b     = (const float*)d_in[6];
    const float* Wr_b     = (const float*)d_in[7];
    const float* b_b      = (const float*)d_in[8];
    const float* W1       = (const float*)d_in[9];
    const float* b1       = (const float*)d_in[10];
    const float* W2       = (const float*)d_in[11];
    const float* b2       = (const float*)d_in[12];
    const float* We       = (const float*)d_in[13];
    const float* be       = (const float*)d_in[14];
    const float* Ws       = (const float*)d_in[15];
    const float* bs       = (const float*)d_in[16];

    float* ws     = (float*)d_ws;
    float* Xf     = ws;                      // [2048,600]
    float* Xb     = Xf + (long)SEQ * G4;     // [2048,600]
    float* hidden = Xb + (long)SEQ * G4;     // [2048,300]
    float* outm   = hidden + (long)SEQ * H1; // [2048,300]
    float* whh    = outm + (long)SEQ * H1;   // [2048,300]
    float* H      = whh + (long)SEQ * H1;    // [300]

    float* outp = (float*)d_out;

    xpre_kernel<<<dim3(SEQ / 8, 2), 640, 0, stream>>>(sentence, emb, Wk_f, b_f, Wk_b, b_b, Xf, Xb);
    lstm_scan_kernel<<<2, 640, 0, stream>>>(Xf, Xb, Wr_f, Wr_b, hidden);
    w1_kernel<<<SEQ / 8, 320, 0, stream>>>(hidden, W1, b1, outm);
    attn_kernel<<<SEQ, 320, 0, stream>>>(sentence, syn_idx, emb, outm, hidden, W2, b2, whh);
    hred_kernel<<<H1, 256, 0, stream>>>(whh, H);
    logits_kernel<<<1, 64, 0, stream>>>(H, We, be, Ws, bs, outp);
}

// Round 3
// 4132.521 us; speedup vs baseline: 1.0126x; 1.0126x over previous
//
#include <hip/hip_runtime.h>
#include <hip/hip_bf16.h>

#define SEQ   2048
#define DIM   300
#define UU    150
#define G4    600   // 4*U
#define H1    300
#define NSYN  4

static __device__ __forceinline__ float sigm(float x) { return 1.0f / (1.0f + __expf(-x)); }
static __device__ __forceinline__ float tanh_fast(float x) { return 1.0f - 2.0f / (1.0f + __expf(2.0f * x)); }

// ---------------------------------------------------------------------------
// Kernel A: emb = embedding[sentence];  Xpre_dir = emb @ Wk_dir + b_dir
// grid (SEQ/8, 2), block 640
// ---------------------------------------------------------------------------
__global__ void xpre_kernel(const int* __restrict__ sentence,
                            const float* __restrict__ emb_mat,
                            const float* __restrict__ Wk_f,
                            const float* __restrict__ b_f,
                            const float* __restrict__ Wk_b,
                            const float* __restrict__ b_b,
                            float* __restrict__ Xf, float* __restrict__ Xb)
{
    const int dir = blockIdx.y;
    const float* Wk = dir ? Wk_b : Wk_f;
    const float* bb = dir ? b_b : b_f;
    float* X = dir ? Xb : Xf;

    const int s0  = blockIdx.x * 8;
    const int tid = threadIdx.x;

    __shared__ int   sids[8];
    __shared__ float embs[8][DIM];

    if (tid < 8) sids[tid] = sentence[s0 + tid];
    __syncthreads();
    for (int e = tid; e < 8 * DIM; e += 640) {
        int r = e / DIM, d = e - r * DIM;
        embs[r][d] = emb_mat[(long)sids[r] * DIM + d];
    }
    __syncthreads();

    if (tid < G4) {
        float acc[8];
        float bv = bb[tid];
        #pragma unroll
        for (int r = 0; r < 8; ++r) acc[r] = bv;
        for (int k = 0; k < DIM; ++k) {
            float wv = Wk[k * G4 + tid];
            #pragma unroll
            for (int r = 0; r < 8; ++r) acc[r] = fmaf(embs[r][k], wv, acc[r]);
        }
        #pragma unroll
        for (int r = 0; r < 8; ++r) X[(long)(s0 + r) * G4 + tid] = acc[r];
    }
}

// ---------------------------------------------------------------------------
// Kernel B: sequential LSTM scan, one block per direction.
// 640 threads; threads 0..599 each own one Wr column: 150 fp32 weights held in
// NAMED float4/float2 registers (37x4 + 2 = 150) so the compiler cannot demote
// them to scratch. h broadcast from LDS via float4 (ds_read_b128, broadcast).
// ---------------------------------------------------------------------------
#define REP37(F) F(0) F(1) F(2) F(3) F(4) F(5) F(6) F(7) F(8) F(9) \
                 F(10) F(11) F(12) F(13) F(14) F(15) F(16) F(17) F(18) F(19) \
                 F(20) F(21) F(22) F(23) F(24) F(25) F(26) F(27) F(28) F(29) \
                 F(30) F(31) F(32) F(33) F(34) F(35) F(36)

__global__ __launch_bounds__(640, 3) void lstm_scan_kernel(
    const float* __restrict__ Xf, const float* __restrict__ Xb,
    const float* __restrict__ Wr_f, const float* __restrict__ Wr_b,
    float* __restrict__ hidden)
{
    const int dir = blockIdx.x;
    const float* X  = dir ? Xb : Xf;
    const float* Wr = dir ? Wr_b : Wr_f;
    const int tid = threadIdx.x;

    __shared__ __align__(16) float hs[UU + 2];  // +2 pad keeps float4 reads simple
    __shared__ float zs[G4];

    const float4* hs4 = (const float4*)hs;

    // --- weights in named registers ---
#define WDECL(i) float4 w##i;
    REP37(WDECL)
#undef WDECL
    float2 wt;

    if (tid < G4) {
#define WLOAD(i) w##i = make_float4(Wr[(4*i+0)*G4 + tid], Wr[(4*i+1)*G4 + tid], \
                                    Wr[(4*i+2)*G4 + tid], Wr[(4*i+3)*G4 + tid]);
        REP37(WLOAD)
#undef WLOAD
        wt = make_float2(Wr[148 * G4 + tid], Wr[149 * G4 + tid]);
    }

    if (tid < UU + 2) hs[tid] = 0.0f;
    float c = 0.0f;

    int t = dir ? (SEQ - 1) : 0;
    const int dG = dir ? -G4 : G4;
    int xoff = t * G4 + tid;
    float xcur = (tid < G4) ? X[xoff] : 0.0f;
    __syncthreads();

    for (int step = 0; step < SEQ; ++step) {
        // prefetch next step's pre-activation (hidden under the dot chain)
        const int xoff_n = (step < SEQ - 1) ? (xoff + dG) : xoff;
        float xnext = (tid < G4) ? X[xoff_n] : 0.0f;

        if (tid < G4) {
            float a0 = xcur, a1 = 0.0f;
#define WFMA(i) { float4 h4 = hs4[i]; \
                  a0 = fmaf(w##i.x, h4.x, a0); \
                  a1 = fmaf(w##i.y, h4.y, a1); \
                  a0 = fmaf(w##i.z, h4.z, a0); \
                  a1 = fmaf(w##i.w, h4.w, a1); }
            REP37(WFMA)
#undef WFMA
            {
                a0 = fmaf(wt.x, hs[148], a0);
                a1 = fmaf(wt.y, hs[149], a1);
            }
            zs[tid] = a0 + a1;
        }
        __syncthreads();

        if (tid < UU) {
            float zi = zs[tid], zf = zs[UU + tid], zg = zs[2 * UU + tid], zo = zs[3 * UU + tid];
            float ig = sigm(zi);
            float fg = sigm(zf);
            float gg = tanh_fast(zg);
            float og = sigm(zo);
            c = fg * c + ig * gg;
            float hv = og * tanh_fast(c);
            hs[tid] = hv;
            hidden[(long)t * H1 + dir * UU + tid] = hv;
        }
        __syncthreads();

        xcur = xnext;
        xoff = xoff_n;
        t += dir ? -1 : 1;
    }
}

// ---------------------------------------------------------------------------
// Kernel C: out = hidden @ W1 + b1   [2048,300]x[300,300]
// grid SEQ/8, block 320
// ---------------------------------------------------------------------------
__global__ void w1_kernel(const float* __restrict__ hidden,
                          const float* __restrict__ W1,
                          const float* __restrict__ b1,
                          float* __restrict__ outm)
{
    const int s0  = blockIdx.x * 8;
    const int tid = threadIdx.x;
    __shared__ float hl[8][H1];
    for (int e = tid; e < 8 * H1; e += 320)
        hl[e / H1][e - (e / H1) * H1] = hidden[(long)s0 * H1 + e];
    __syncthreads();

    if (tid < H1) {
        float acc[8];
        float bv = b1[tid];
        #pragma unroll
        for (int r = 0; r < 8; ++r) acc[r] = bv;
        for (int k = 0; k < H1; ++k) {
            float wv = W1[k * H1 + tid];
            #pragma unroll
            for (int r = 0; r < 8; ++r) acc[r] = fmaf(hl[r][k], wv, acc[r]);
        }
        #pragma unroll
        for (int r = 0; r < 8; ++r) outm[(long)(s0 + r) * H1 + tid] = acc[r];
    }
}

// ---------------------------------------------------------------------------
// Block reductions for 320-thread blocks (5 waves)
// ---------------------------------------------------------------------------
static __device__ __forceinline__ float4 blockReduce4(float4 v, float* red, int tid)
{
    #pragma unroll
    for (int off = 32; off > 0; off >>= 1) {
        v.x += __shfl_down(v.x, off);
        v.y += __shfl_down(v.y, off);
        v.z += __shfl_down(v.z, off);
        v.w += __shfl_down(v.w, off);
    }
    __syncthreads();
    if ((tid & 63) == 0) {
        int wv = tid >> 6;
        red[wv * 4 + 0] = v.x; red[wv * 4 + 1] = v.y;
        red[wv * 4 + 2] = v.z; red[wv * 4 + 3] = v.w;
    }
    __syncthreads();
    float4 r;
    r.x = red[0]; r.y = red[1]; r.z = red[2]; r.w = red[3];
    #pragma unroll
    for (int wv = 1; wv < 5; ++wv) {
        r.x += red[wv * 4 + 0]; r.y += red[wv * 4 + 1];
        r.z += red[wv * 4 + 2]; r.w += red[wv * 4 + 3];
    }
    return r;
}

static __device__ __forceinline__ float blockReduce1(float v, float* red, int tid)
{
    #pragma unroll
    for (int off = 32; off > 0; off >>= 1) v += __shfl_down(v, off);
    __syncthreads();
    if ((tid & 63) == 0) red[tid >> 6] = v;
    __syncthreads();
    return red[0] + red[1] + red[2] + red[3] + red[4];
}

// ---------------------------------------------------------------------------
// Kernel D: per-position synonym attention; writes whh[s][d] = c2[s]*h_hat[s][d]
// grid SEQ, block 320
// ---------------------------------------------------------------------------
__global__ void attn_kernel(const int* __restrict__ sentence,
                            const int* __restrict__ syn_idx,
                            const float* __restrict__ emb_mat,
                            const float* __restrict__ outm,
                            const float* __restrict__ hidden,
                            const float* __restrict__ W2,
                            const float* __restrict__ b2,
                            float* __restrict__ whh)
{
    const int s   = blockIdx.x;
    const int t   = s ? (s - 1) : 0;
    const int tid = threadIdx.x;
    __shared__ float red[20];

    const int sent = sentence[s];
    const long i0 = (long)syn_idx[sent * NSYN + 0] * DIM;
    const long i1 = (long)syn_idx[sent * NSYN + 1] * DIM;
    const long i2 = (long)syn_idx[sent * NSYN + 2] * DIM;
    const long i3 = (long)syn_idx[sent * NSYN + 3] * DIM;

    float se0 = 0.f, se1 = 0.f, se2 = 0.f, se3 = 0.f, od = 0.f, hd = 0.f;
    if (tid < DIM) {
        se0 = emb_mat[i0 + tid];
        se1 = emb_mat[i1 + tid];
        se2 = emb_mat[i2 + tid];
        se3 = emb_mat[i3 + tid];
        od  = outm[(long)t * H1 + tid];
        hd  = hidden[(long)t * H1 + tid];
    }

    float4 dots = blockReduce4(make_float4(se0 * od, se1 * od, se2 * od, se3 * od), red, tid);
    float c0 = __expf(dots.x), c1 = __expf(dots.y), c2c = __expf(dots.z), c3 = __expf(dots.w);

    float hh = fmaf(c0, se0, fmaf(c1, se1, fmaf(c2c, se2, fmaf(c3, se3, hd))));

    float w2v = (tid < DIM) ? W2[tid] : 0.f;
    float dot2 = blockReduce1(hh * w2v, red, tid);
    float cc = __expf(tanh_fast(dot2 + b2[0]));

    if (tid < DIM) whh[(long)s * H1 + tid] = cc * hh;
}

// ---------------------------------------------------------------------------
// Kernel E: H[d] = sum_s whh[s][d]      grid H1, block 256
// ---------------------------------------------------------------------------
__global__ void hred_kernel(const float* __restrict__ whh, float* __restrict__ H)
{
    const int d   = blockIdx.x;
    const int tid = threadIdx.x;
    float acc = 0.f;
    for (int s = tid; s < SEQ; s += 256) acc += whh[(long)s * H1 + d];
    #pragma unroll
    for (int off = 32; off > 0; off >>= 1) acc += __shfl_down(acc, off);
    __shared__ float red[4];
    if ((tid & 63) == 0) red[tid >> 6] = acc;
    __syncthreads();
    if (tid == 0) H[d] = red[0] + red[1] + red[2] + red[3];
}

// ---------------------------------------------------------------------------
// Kernel F: logits. out[0..7]=H@We+be, out[8]=H@Ws+bs.  1 block, 64 threads
// ---------------------------------------------------------------------------
__global__ void logits_kernel(const float* __restrict__ H,
                              const float* __restrict__ We,
                              const float* __restrict__ be,
                              const float* __restrict__ Ws,
                              const float* __restrict__ bs,
                              float* __restrict__ outp)
{
    const int e = threadIdx.x;
    if (e < 9) {
        float acc = (e < 8) ? be[e] : bs[0];
        for (int d = 0; d < H1; ++d) {
            float wv = (e < 8) ? We[d * 8 + e] : Ws[d];
            acc = fmaf(H[d], wv, acc);
        }
        outp[e] = acc;
    }
}

// ---------------------------------------------------------------------------
extern "C" void kernel_launch(void* const* d_in, const int* in_sizes, int n_in,
                              void* d_out, int out_size, void* d_ws, size_t ws_size,
                              hipStream_t stream)
{
    const int* sentence   = (const int*)d_in[0];
    const int* syn_idx    = (const int*)d_in[1];
    const float* emb      = (const float*)d_in[2];
    const float* Wk_f     = (const float*)d_in[3];
    const float* Wr_f     = (const float*)d_in[4];
    const float* b_f      = (const float*)d_in[5];
    const float* Wk_b     = (const float*)d_in[6];
    const float* Wr_b     = (const float*)d_in[7];
    const float* b_b      = (const float*)d_in[8];
    const float* W1       = (const float*)d_in[9];
    const float* b1       = (const float*)d_in[10];
    const float* W2       = (const float*)d_in[11];
    const float* b2       = (const float*)d_in[12];
    const float* We       = (const float*)d_in[13];
    const float* be       = (const float*)d_in[14];
    const float* Ws       = (const float*)d_in[15];
    const float* bs       = (const float*)d_in[16];

    float* ws     = (float*)d_ws;
    float* Xf     = ws;                      // [2048,600]
    float* Xb     = Xf + (long)SEQ * G4;     // [2048,600]
    float* hidden = Xb + (long)SEQ * G4;     // [2048,300]
    float* outm   = hidden + (long)SEQ * H1; // [2048,300]
    float* whh    = outm + (long)SEQ * H1;   // [2048,300]
    float* H      = whh + (long)SEQ * H1;    // [300]

    float* outp = (float*)d_out;

    xpre_kernel<<<dim3(SEQ / 8, 2), 640, 0, stream>>>(sentence, emb, Wk_f, b_f, Wk_b, b_b, Xf, Xb);
    lstm_scan_kernel<<<2, 640, 0, stream>>>(Xf, Xb, Wr_f, Wr_b, hidden);
    w1_kernel<<<SEQ / 8, 320, 0, stream>>>(hidden, W1, b1, outm);
    attn_kernel<<<SEQ, 320, 0, stream>>>(sentence, syn_idx, emb, outm, hidden, W2, b2, whh);
    hred_kernel<<<H1, 256, 0, stream>>>(whh, H);
    logits_kernel<<<1, 64, 0, stream>>>(H, We, be, Ws, bs, outp);
}

// Round 4
// 2383.233 us; speedup vs baseline: 1.7558x; 1.7340x over previous
//
#include <hip/hip_runtime.h>
#include <hip/hip_bf16.h>

#define SEQ   2048
#define DIM   300
#define UU    150
#define G4    600   // 4*U
#define H1    300
#define NSYN  4

typedef _Float16 half2v __attribute__((ext_vector_type(2)));
union HU { unsigned u; half2v h; };

static __device__ __forceinline__ float sigm(float x) { return 1.0f / (1.0f + __expf(-x)); }
static __device__ __forceinline__ float tanh_fast(float x) { return 1.0f - 2.0f / (1.0f + __expf(2.0f * x)); }

#if defined(__has_builtin)
#if __has_builtin(__builtin_amdgcn_fdot2)
#define HAVE_FDOT2 1
#endif
#endif

static __device__ __forceinline__ float dot2acc(unsigned w, unsigned h, float acc) {
    HU uw, uh; uw.u = w; uh.u = h;
#ifdef HAVE_FDOT2
    return __builtin_amdgcn_fdot2(uw.h, uh.h, acc, false);
#else
    acc = fmaf((float)uw.h.x, (float)uh.h.x, acc);
    return fmaf((float)uw.h.y, (float)uh.h.y, acc);
#endif
}

// ---------------------------------------------------------------------------
// Kernel A: emb = embedding[sentence];  Xpre_dir = emb @ Wk_dir + b_dir
// ---------------------------------------------------------------------------
__global__ void xpre_kernel(const int* __restrict__ sentence,
                            const float* __restrict__ emb_mat,
                            const float* __restrict__ Wk_f,
                            const float* __restrict__ b_f,
                            const float* __restrict__ Wk_b,
                            const float* __restrict__ b_b,
                            float* __restrict__ Xf, float* __restrict__ Xb)
{
    const int dir = blockIdx.y;
    const float* Wk = dir ? Wk_b : Wk_f;
    const float* bb = dir ? b_b : b_f;
    float* X = dir ? Xb : Xf;

    const int s0  = blockIdx.x * 8;
    const int tid = threadIdx.x;

    __shared__ int   sids[8];
    __shared__ float embs[8][DIM];

    if (tid < 8) sids[tid] = sentence[s0 + tid];
    __syncthreads();
    for (int e = tid; e < 8 * DIM; e += 640) {
        int r = e / DIM, d = e - r * DIM;
        embs[r][d] = emb_mat[(long)sids[r] * DIM + d];
    }
    __syncthreads();

    if (tid < G4) {
        float acc[8];
        float bv = bb[tid];
        #pragma unroll
        for (int r = 0; r < 8; ++r) acc[r] = bv;
        for (int k = 0; k < DIM; ++k) {
            float wv = Wk[k * G4 + tid];
            #pragma unroll
            for (int r = 0; r < 8; ++r) acc[r] = fmaf(embs[r][k], wv, acc[r]);
        }
        #pragma unroll
        for (int r = 0; r < 8; ++r) X[(long)(s0 + r) * G4 + tid] = acc[r];
    }
}

// ---------------------------------------------------------------------------
// Kernel B: LSTM scan. 2 blocks (one per direction), 256 threads (4 waves,
// 1 wave/SIMD -> 512-reg budget via amdgpu_waves_per_eu(1,1)).
// Thread owns cols c0=tid, c1=tid+256, c2=tid+512 (tid<88).
// Weights: f16 pairs (over u) in named registers. h: f16 pairs in LDS,
// lane-distributed loads + readlane broadcast. Accumulate fp32 (v_dot2_f32_f16).
// ---------------------------------------------------------------------------
#define REP75(F) \
  F(0) F(1) F(2) F(3) F(4) F(5) F(6) F(7) F(8) F(9) \
  F(10) F(11) F(12) F(13) F(14) F(15) F(16) F(17) F(18) F(19) \
  F(20) F(21) F(22) F(23) F(24) F(25) F(26) F(27) F(28) F(29) \
  F(30) F(31) F(32) F(33) F(34) F(35) F(36) F(37) F(38) F(39) \
  F(40) F(41) F(42) F(43) F(44) F(45) F(46) F(47) F(48) F(49) \
  F(50) F(51) F(52) F(53) F(54) F(55) F(56) F(57) F(58) F(59) \
  F(60) F(61) F(62) F(63) F(64) F(65) F(66) F(67) F(68) F(69) \
  F(70) F(71) F(72) F(73) F(74)

static __device__ __forceinline__ unsigned packpair(const float* __restrict__ Wr, int c, int k) {
    HU x;
    x.h.x = (_Float16)Wr[(2 * k) * G4 + c];
    x.h.y = (_Float16)Wr[(2 * k + 1) * G4 + c];
    return x.u;
}

__global__ __launch_bounds__(256) __attribute__((amdgpu_waves_per_eu(1, 1)))
void lstm_scan_kernel(
    const float* __restrict__ Xf, const float* __restrict__ Xb,
    const float* __restrict__ Wr_f, const float* __restrict__ Wr_b,
    float* __restrict__ hidden)
{
    const int dir = blockIdx.x;
    const float* X  = dir ? Xb : Xf;
    const float* Wr = dir ? Wr_b : Wr_f;
    const int tid  = threadIdx.x;
    const int lane = tid & 63;

    __shared__ float zs[G4];
    __shared__ __align__(4) _Float16 hs16[256];   // 128 packed pairs, zero-padded

    const int c0 = tid;
    const int c1 = tid + 256;
    const bool has2 = (tid < 88);
    const int c2 = has2 ? (tid + 512) : 599;

    // --- f16-packed weights in named registers ---
#define WDECL(k) unsigned wA_##k, wB_##k, wC_##k;
    REP75(WDECL)
#undef WDECL
#define WLOAD(k) wA_##k = packpair(Wr, c0, k); wB_##k = packpair(Wr, c1, k); wC_##k = packpair(Wr, c2, k);
    REP75(WLOAD)
#undef WLOAD

    if (tid < 128) ((unsigned*)hs16)[tid] = 0u;   // h = 0
    float c = 0.0f;

    int t = dir ? (SEQ - 1) : 0;
    const int dt = dir ? -1 : 1;
    float x0 = X[t * G4 + c0];
    float x1 = X[t * G4 + c1];
    float x2 = X[t * G4 + c2];
    __syncthreads();

    const unsigned* hp = (const unsigned*)hs16;

    for (int step = 0; step < SEQ; ++step) {
        const int tn = (step < SEQ - 1) ? (t + dt) : t;
        // prefetch next x
        float xn0 = X[tn * G4 + c0];
        float xn1 = X[tn * G4 + c1];
        float xn2 = X[tn * G4 + c2];

        // lane-distributed h pairs (written by gate phase of previous step)
        unsigned hr0 = hp[lane];
        unsigned hr1 = hp[64 + lane];

        float a0 = x0, a1 = x1, a2 = x2;
#define DOT(k) { unsigned hk = (unsigned)(((k) < 64) ? __builtin_amdgcn_readlane((int)hr0, (k)) \
                                                     : __builtin_amdgcn_readlane((int)hr1, (k) - 64)); \
                 a0 = dot2acc(wA_##k, hk, a0); \
                 a1 = dot2acc(wB_##k, hk, a1); \
                 a2 = dot2acc(wC_##k, hk, a2); }
        REP75(DOT)
#undef DOT

        zs[c0] = a0;
        zs[c1] = a1;
        if (has2) zs[c2] = a2;
        __syncthreads();

        if (tid < UU) {
            float zi = zs[tid], zf = zs[UU + tid], zg = zs[2 * UU + tid], zo = zs[3 * UU + tid];
            float ig = sigm(zi);
            float fg = sigm(zf);
            float gg = tanh_fast(zg);
            float og = sigm(zo);
            c = fg * c + ig * gg;
            float hv = og * tanh_fast(c);
            hs16[tid] = (_Float16)hv;
            hidden[(long)t * H1 + dir * UU + tid] = hv;
        }
        __syncthreads();

        x0 = xn0; x1 = xn1; x2 = xn2;
        t = tn;
    }
}

// ---------------------------------------------------------------------------
// Kernel C: out = hidden @ W1 + b1   [2048,300]x[300,300]
// ---------------------------------------------------------------------------
__global__ void w1_kernel(const float* __restrict__ hidden,
                          const float* __restrict__ W1,
                          const float* __restrict__ b1,
                          float* __restrict__ outm)
{
    const int s0  = blockIdx.x * 8;
    const int tid = threadIdx.x;
    __shared__ float hl[8][H1];
    for (int e = tid; e < 8 * H1; e += 320)
        hl[e / H1][e - (e / H1) * H1] = hidden[(long)s0 * H1 + e];
    __syncthreads();

    if (tid < H1) {
        float acc[8];
        float bv = b1[tid];
        #pragma unroll
        for (int r = 0; r < 8; ++r) acc[r] = bv;
        for (int k = 0; k < H1; ++k) {
            float wv = W1[k * H1 + tid];
            #pragma unroll
            for (int r = 0; r < 8; ++r) acc[r] = fmaf(hl[r][k], wv, acc[r]);
        }
        #pragma unroll
        for (int r = 0; r < 8; ++r) outm[(long)(s0 + r) * H1 + tid] = acc[r];
    }
}

// ---------------------------------------------------------------------------
// Block reductions for 320-thread blocks (5 waves)
// ---------------------------------------------------------------------------
static __device__ __forceinline__ float4 blockReduce4(float4 v, float* red, int tid)
{
    #pragma unroll
    for (int off = 32; off > 0; off >>= 1) {
        v.x += __shfl_down(v.x, off);
        v.y += __shfl_down(v.y, off);
        v.z += __shfl_down(v.z, off);
        v.w += __shfl_down(v.w, off);
    }
    __syncthreads();
    if ((tid & 63) == 0) {
        int wv = tid >> 6;
        red[wv * 4 + 0] = v.x; red[wv * 4 + 1] = v.y;
        red[wv * 4 + 2] = v.z; red[wv * 4 + 3] = v.w;
    }
    __syncthreads();
    float4 r;
    r.x = red[0]; r.y = red[1]; r.z = red[2]; r.w = red[3];
    #pragma unroll
    for (int wv = 1; wv < 5; ++wv) {
        r.x += red[wv * 4 + 0]; r.y += red[wv * 4 + 1];
        r.z += red[wv * 4 + 2]; r.w += red[wv * 4 + 3];
    }
    return r;
}

static __device__ __forceinline__ float blockReduce1(float v, float* red, int tid)
{
    #pragma unroll
    for (int off = 32; off > 0; off >>= 1) v += __shfl_down(v, off);
    __syncthreads();
    if ((tid & 63) == 0) red[tid >> 6] = v;
    __syncthreads();
    return red[0] + red[1] + red[2] + red[3] + red[4];
}

// ---------------------------------------------------------------------------
// Kernel D: per-position synonym attention; whh[s][d] = c2[s]*h_hat[s][d]
// ---------------------------------------------------------------------------
__global__ void attn_kernel(const int* __restrict__ sentence,
                            const int* __restrict__ syn_idx,
                            const float* __restrict__ emb_mat,
                            const float* __restrict__ outm,
                            const float* __restrict__ hidden,
                            const float* __restrict__ W2,
                            const float* __restrict__ b2,
                            float* __restrict__ whh)
{
    const int s   = blockIdx.x;
    const int t   = s ? (s - 1) : 0;
    const int tid = threadIdx.x;
    __shared__ float red[20];

    const int sent = sentence[s];
    const long i0 = (long)syn_idx[sent * NSYN + 0] * DIM;
    const long i1 = (long)syn_idx[sent * NSYN + 1] * DIM;
    const long i2 = (long)syn_idx[sent * NSYN + 2] * DIM;
    const long i3 = (long)syn_idx[sent * NSYN + 3] * DIM;

    float se0 = 0.f, se1 = 0.f, se2 = 0.f, se3 = 0.f, od = 0.f, hd = 0.f;
    if (tid < DIM) {
        se0 = emb_mat[i0 + tid];
        se1 = emb_mat[i1 + tid];
        se2 = emb_mat[i2 + tid];
        se3 = emb_mat[i3 + tid];
        od  = outm[(long)t * H1 + tid];
        hd  = hidden[(long)t * H1 + tid];
    }

    float4 dots = blockReduce4(make_float4(se0 * od, se1 * od, se2 * od, se3 * od), red, tid);
    float c0 = __expf(dots.x), c1 = __expf(dots.y), c2c = __expf(dots.z), c3 = __expf(dots.w);

    float hh = fmaf(c0, se0, fmaf(c1, se1, fmaf(c2c, se2, fmaf(c3, se3, hd))));

    float w2v = (tid < DIM) ? W2[tid] : 0.f;
    float dot2 = blockReduce1(hh * w2v, red, tid);
    float cc = __expf(tanh_fast(dot2 + b2[0]));

    if (tid < DIM) whh[(long)s * H1 + tid] = cc * hh;
}

// ---------------------------------------------------------------------------
// Kernel E: H[d] = sum_s whh[s][d]
// ---------------------------------------------------------------------------
__global__ void hred_kernel(const float* __restrict__ whh, float* __restrict__ H)
{
    const int d   = blockIdx.x;
    const int tid = threadIdx.x;
    float acc = 0.f;
    for (int s = tid; s < SEQ; s += 256) acc += whh[(long)s * H1 + d];
    #pragma unroll
    for (int off = 32; off > 0; off >>= 1) acc += __shfl_down(acc, off);
    __shared__ float red[4];
    if ((tid & 63) == 0) red[tid >> 6] = acc;
    __syncthreads();
    if (tid == 0) H[d] = red[0] + red[1] + red[2] + red[3];
}

// ---------------------------------------------------------------------------
// Kernel F: logits
// ---------------------------------------------------------------------------
__global__ void logits_kernel(const float* __restrict__ H,
                              const float* __restrict__ We,
                              const float* __restrict__ be,
                              const float* __restrict__ Ws,
                              const float* __restrict__ bs,
                              float* __restrict__ outp)
{
    const int e = threadIdx.x;
    if (e < 9) {
        float acc = (e < 8) ? be[e] : bs[0];
        for (int d = 0; d < H1; ++d) {
            float wv = (e < 8) ? We[d * 8 + e] : Ws[d];
            acc = fmaf(H[d], wv, acc);
        }
        outp[e] = acc;
    }
}

// ---------------------------------------------------------------------------
extern "C" void kernel_launch(void* const* d_in, const int* in_sizes, int n_in,
                              void* d_out, int out_size, void* d_ws, size_t ws_size,
                              hipStream_t stream)
{
    const int* sentence   = (const int*)d_in[0];
    const int* syn_idx    = (const int*)d_in[1];
    const float* emb      = (const float*)d_in[2];
    const float* Wk_f     = (const float*)d_in[3];
    const float* Wr_f     = (const float*)d_in[4];
    const float* b_f      = (const float*)d_in[5];
    const float* Wk_b     = (const float*)d_in[6];
    const float* Wr_b     = (const float*)d_in[7];
    const float* b_b      = (const float*)d_in[8];
    const float* W1       = (const float*)d_in[9];
    const float* b1       = (const float*)d_in[10];
    const float* W2       = (const float*)d_in[11];
    const float* b2       = (const float*)d_in[12];
    const float* We       = (const float*)d_in[13];
    const float* be       = (const float*)d_in[14];
    const float* Ws       = (const float*)d_in[15];
    const float* bs       = (const float*)d_in[16];

    float* ws     = (float*)d_ws;
    float* Xf     = ws;                      // [2048,600]
    float* Xb     = Xf + (long)SEQ * G4;     // [2048,600]
    float* hidden = Xb + (long)SEQ * G4;     // [2048,300]
    float* outm   = hidden + (long)SEQ * H1; // [2048,300]
    float* whh    = outm + (long)SEQ * H1;   // [2048,300]
    float* H      = whh + (long)SEQ * H1;    // [300]

    float* outp = (float*)d_out;

    xpre_kernel<<<dim3(SEQ / 8, 2), 640, 0, stream>>>(sentence, emb, Wk_f, b_f, Wk_b, b_b, Xf, Xb);
    lstm_scan_kernel<<<2, 256, 0, stream>>>(Xf, Xb, Wr_f, Wr_b, hidden);
    w1_kernel<<<SEQ / 8, 320, 0, stream>>>(hidden, W1, b1, outm);
    attn_kernel<<<SEQ, 320, 0, stream>>>(sentence, syn_idx, emb, outm, hidden, W2, b2, whh);
    hred_kernel<<<H1, 256, 0, stream>>>(whh, H);
    logits_kernel<<<1, 64, 0, stream>>>(H, We, be, Ws, bs, outp);
}

// Round 5
// 2358.037 us; speedup vs baseline: 1.7746x; 1.0107x over previous
//
#include <hip/hip_runtime.h>
#include <hip/hip_bf16.h>

#define SEQ   2048
#define DIM   300
#define UU    150
#define G4    600   // 4*U
#define H1    300
#define NSYN  4

typedef _Float16 half2v __attribute__((ext_vector_type(2)));
union HU { unsigned u; half2v h; };

static __device__ __forceinline__ float sigm(float x) { return 1.0f / (1.0f + __expf(-x)); }
static __device__ __forceinline__ float tanh_fast(float x) { return 1.0f - 2.0f / (1.0f + __expf(2.0f * x)); }

#if defined(__has_builtin)
#if __has_builtin(__builtin_amdgcn_fdot2)
#define HAVE_FDOT2 1
#endif
#endif

static __device__ __forceinline__ float dot2acc(unsigned w, unsigned h, float acc) {
    HU uw, uh; uw.u = w; uh.u = h;
#ifdef HAVE_FDOT2
    return __builtin_amdgcn_fdot2(uw.h, uh.h, acc, false);
#else
    acc = fmaf((float)uw.h.x, (float)uh.h.x, acc);
    return fmaf((float)uw.h.y, (float)uh.h.y, acc);
#endif
}

// LDS-only barrier: drains lgkmcnt (LDS) but NOT vmcnt — avoids the
// __syncthreads-mandated vmcnt(0) drain of the per-step hidden[] store
// and x prefetch loads (that drain cost ~1600 cyc/step in R4).
#define LDS_BARRIER() asm volatile("s_waitcnt lgkmcnt(0)\n\ts_barrier" ::: "memory")

// ---------------------------------------------------------------------------
// Kernel A: emb = embedding[sentence];  Xpre_dir = emb @ Wk_dir + b_dir
// ---------------------------------------------------------------------------
__global__ void xpre_kernel(const int* __restrict__ sentence,
                            const float* __restrict__ emb_mat,
                            const float* __restrict__ Wk_f,
                            const float* __restrict__ b_f,
                            const float* __restrict__ Wk_b,
                            const float* __restrict__ b_b,
                            float* __restrict__ Xf, float* __restrict__ Xb)
{
    const int dir = blockIdx.y;
    const float* Wk = dir ? Wk_b : Wk_f;
    const float* bb = dir ? b_b : b_f;
    float* X = dir ? Xb : Xf;

    const int s0  = blockIdx.x * 8;
    const int tid = threadIdx.x;

    __shared__ int   sids[8];
    __shared__ float embs[8][DIM];

    if (tid < 8) sids[tid] = sentence[s0 + tid];
    __syncthreads();
    for (int e = tid; e < 8 * DIM; e += 640) {
        int r = e / DIM, d = e - r * DIM;
        embs[r][d] = emb_mat[(long)sids[r] * DIM + d];
    }
    __syncthreads();

    if (tid < G4) {
        float acc[8];
        float bv = bb[tid];
        #pragma unroll
        for (int r = 0; r < 8; ++r) acc[r] = bv;
        for (int k = 0; k < DIM; ++k) {
            float wv = Wk[k * G4 + tid];
            #pragma unroll
            for (int r = 0; r < 8; ++r) acc[r] = fmaf(embs[r][k], wv, acc[r]);
        }
        #pragma unroll
        for (int r = 0; r < 8; ++r) X[(long)(s0 + r) * G4 + tid] = acc[r];
    }
}

// ---------------------------------------------------------------------------
// Kernel B: LSTM scan. 2 blocks (one per direction), 256 threads.
// f16-packed weights in registers (225 regs), h broadcast via readlane,
// LDS-only barriers between phases.
// ---------------------------------------------------------------------------
#define REP75(F) \
  F(0) F(1) F(2) F(3) F(4) F(5) F(6) F(7) F(8) F(9) \
  F(10) F(11) F(12) F(13) F(14) F(15) F(16) F(17) F(18) F(19) \
  F(20) F(21) F(22) F(23) F(24) F(25) F(26) F(27) F(28) F(29) \
  F(30) F(31) F(32) F(33) F(34) F(35) F(36) F(37) F(38) F(39) \
  F(40) F(41) F(42) F(43) F(44) F(45) F(46) F(47) F(48) F(49) \
  F(50) F(51) F(52) F(53) F(54) F(55) F(56) F(57) F(58) F(59) \
  F(60) F(61) F(62) F(63) F(64) F(65) F(66) F(67) F(68) F(69) \
  F(70) F(71) F(72) F(73) F(74)

static __device__ __forceinline__ unsigned packpair(const float* __restrict__ Wr, int c, int k) {
    HU x;
    x.h.x = (_Float16)Wr[(2 * k) * G4 + c];
    x.h.y = (_Float16)Wr[(2 * k + 1) * G4 + c];
    return x.u;
}

__global__ __launch_bounds__(256) __attribute__((amdgpu_waves_per_eu(1, 1)))
void lstm_scan_kernel(
    const float* __restrict__ Xf, const float* __restrict__ Xb,
    const float* __restrict__ Wr_f, const float* __restrict__ Wr_b,
    float* __restrict__ hidden)
{
    const int dir = blockIdx.x;
    const float* X  = dir ? Xb : Xf;
    const float* Wr = dir ? Wr_b : Wr_f;
    const int tid  = threadIdx.x;
    const int lane = tid & 63;

    __shared__ float zs[G4];
    __shared__ __align__(4) _Float16 hs16[256];   // 128 packed pairs, zero-padded

    const int c0 = tid;
    const int c1 = tid + 256;
    const bool has2 = (tid < 88);
    const int c2 = has2 ? (tid + 512) : 599;

    // --- f16-packed weights in named registers ---
#define WDECL(k) unsigned wA_##k, wB_##k, wC_##k;
    REP75(WDECL)
#undef WDECL
#define WLOAD(k) wA_##k = packpair(Wr, c0, k); wB_##k = packpair(Wr, c1, k); wC_##k = packpair(Wr, c2, k);
    REP75(WLOAD)
#undef WLOAD

    if (tid < 128) ((unsigned*)hs16)[tid] = 0u;   // h = 0
    float c = 0.0f;

    int t = dir ? (SEQ - 1) : 0;
    const int dt = dir ? -1 : 1;
    float x0 = X[t * G4 + c0];
    float x1 = X[t * G4 + c1];
    float x2 = X[t * G4 + c2];
    __syncthreads();   // once, outside the loop: init visibility

    const unsigned* hp = (const unsigned*)hs16;

    for (int step = 0; step < SEQ; ++step) {
        const int tn = (step < SEQ - 1) ? (t + dt) : t;
        // prefetch next x (consumed next iteration; vmcnt wait overlaps dots)
        float xn0 = X[tn * G4 + c0];
        float xn1 = X[tn * G4 + c1];
        float xn2 = X[tn * G4 + c2];

        // lane-distributed h pairs (written by gate phase of previous step)
        unsigned hr0 = hp[lane];
        unsigned hr1 = hp[64 + lane];

        float a0 = x0, a1 = x1, a2 = x2;
#define DOT(k) { unsigned hk = (unsigned)(((k) < 64) ? __builtin_amdgcn_readlane((int)hr0, (k)) \
                                                     : __builtin_amdgcn_readlane((int)hr1, (k) - 64)); \
                 a0 = dot2acc(wA_##k, hk, a0); \
                 a1 = dot2acc(wB_##k, hk, a1); \
                 a2 = dot2acc(wC_##k, hk, a2); }
        REP75(DOT)
#undef DOT

        zs[c0] = a0;
        zs[c1] = a1;
        if (has2) zs[c2] = a2;
        LDS_BARRIER();

        if (tid < UU) {
            float zi = zs[tid], zf = zs[UU + tid], zg = zs[2 * UU + tid], zo = zs[3 * UU + tid];
            float ig = sigm(zi);
            float fg = sigm(zf);
            float gg = tanh_fast(zg);
            float og = sigm(zo);
            c = fg * c + ig * gg;
            float hv = og * tanh_fast(c);
            hs16[tid] = (_Float16)hv;
            hidden[(long)t * H1 + dir * UU + tid] = hv;   // fire-and-forget
        }
        LDS_BARRIER();

        x0 = xn0; x1 = xn1; x2 = xn2;
        t = tn;
    }
}

// ---------------------------------------------------------------------------
// Kernel C: out = hidden @ W1 + b1   [2048,300]x[300,300]
// ---------------------------------------------------------------------------
__global__ void w1_kernel(const float* __restrict__ hidden,
                          const float* __restrict__ W1,
                          const float* __restrict__ b1,
                          float* __restrict__ outm)
{
    const int s0  = blockIdx.x * 8;
    const int tid = threadIdx.x;
    __shared__ float hl[8][H1];
    for (int e = tid; e < 8 * H1; e += 320)
        hl[e / H1][e - (e / H1) * H1] = hidden[(long)s0 * H1 + e];
    __syncthreads();

    if (tid < H1) {
        float acc[8];
        float bv = b1[tid];
        #pragma unroll
        for (int r = 0; r < 8; ++r) acc[r] = bv;
        for (int k = 0; k < H1; ++k) {
            float wv = W1[k * H1 + tid];
            #pragma unroll
            for (int r = 0; r < 8; ++r) acc[r] = fmaf(hl[r][k], wv, acc[r]);
        }
        #pragma unroll
        for (int r = 0; r < 8; ++r) outm[(long)(s0 + r) * H1 + tid] = acc[r];
    }
}

// ---------------------------------------------------------------------------
// Block reductions for 320-thread blocks (5 waves)
// ---------------------------------------------------------------------------
static __device__ __forceinline__ float4 blockReduce4(float4 v, float* red, int tid)
{
    #pragma unroll
    for (int off = 32; off > 0; off >>= 1) {
        v.x += __shfl_down(v.x, off);
        v.y += __shfl_down(v.y, off);
        v.z += __shfl_down(v.z, off);
        v.w += __shfl_down(v.w, off);
    }
    __syncthreads();
    if ((tid & 63) == 0) {
        int wv = tid >> 6;
        red[wv * 4 + 0] = v.x; red[wv * 4 + 1] = v.y;
        red[wv * 4 + 2] = v.z; red[wv * 4 + 3] = v.w;
    }
    __syncthreads();
    float4 r;
    r.x = red[0]; r.y = red[1]; r.z = red[2]; r.w = red[3];
    #pragma unroll
    for (int wv = 1; wv < 5; ++wv) {
        r.x += red[wv * 4 + 0]; r.y += red[wv * 4 + 1];
        r.z += red[wv * 4 + 2]; r.w += red[wv * 4 + 3];
    }
    return r;
}

static __device__ __forceinline__ float blockReduce1(float v, float* red, int tid)
{
    #pragma unroll
    for (int off = 32; off > 0; off >>= 1) v += __shfl_down(v, off);
    __syncthreads();
    if ((tid & 63) == 0) red[tid >> 6] = v;
    __syncthreads();
    return red[0] + red[1] + red[2] + red[3] + red[4];
}

// ---------------------------------------------------------------------------
// Kernel D: per-position synonym attention; whh[s][d] = c2[s]*h_hat[s][d]
// ---------------------------------------------------------------------------
__global__ void attn_kernel(const int* __restrict__ sentence,
                            const int* __restrict__ syn_idx,
                            const float* __restrict__ emb_mat,
                            const float* __restrict__ outm,
                            const float* __restrict__ hidden,
                            const float* __restrict__ W2,
                            const float* __restrict__ b2,
                            float* __restrict__ whh)
{
    const int s   = blockIdx.x;
    const int t   = s ? (s - 1) : 0;
    const int tid = threadIdx.x;
    __shared__ float red[20];

    const int sent = sentence[s];
    const long i0 = (long)syn_idx[sent * NSYN + 0] * DIM;
    const long i1 = (long)syn_idx[sent * NSYN + 1] * DIM;
    const long i2 = (long)syn_idx[sent * NSYN + 2] * DIM;
    const long i3 = (long)syn_idx[sent * NSYN + 3] * DIM;

    float se0 = 0.f, se1 = 0.f, se2 = 0.f, se3 = 0.f, od = 0.f, hd = 0.f;
    if (tid < DIM) {
        se0 = emb_mat[i0 + tid];
        se1 = emb_mat[i1 + tid];
        se2 = emb_mat[i2 + tid];
        se3 = emb_mat[i3 + tid];
        od  = outm[(long)t * H1 + tid];
        hd  = hidden[(long)t * H1 + tid];
    }

    float4 dots = blockReduce4(make_float4(se0 * od, se1 * od, se2 * od, se3 * od), red, tid);
    float c0 = __expf(dots.x), c1 = __expf(dots.y), c2c = __expf(dots.z), c3 = __expf(dots.w);

    float hh = fmaf(c0, se0, fmaf(c1, se1, fmaf(c2c, se2, fmaf(c3, se3, hd))));

    float w2v = (tid < DIM) ? W2[tid] : 0.f;
    float dot2 = blockReduce1(hh * w2v, red, tid);
    float cc = __expf(tanh_fast(dot2 + b2[0]));

    if (tid < DIM) whh[(long)s * H1 + tid] = cc * hh;
}

// ---------------------------------------------------------------------------
// Kernel E: H[d] = sum_s whh[s][d]
// ---------------------------------------------------------------------------
__global__ void hred_kernel(const float* __restrict__ whh, float* __restrict__ H)
{
    const int d   = blockIdx.x;
    const int tid = threadIdx.x;
    float acc = 0.f;
    for (int s = tid; s < SEQ; s += 256) acc += whh[(long)s * H1 + d];
    #pragma unroll
    for (int off = 32; off > 0; off >>= 1) acc += __shfl_down(acc, off);
    __shared__ float red[4];
    if ((tid & 63) == 0) red[tid >> 6] = acc;
    __syncthreads();
    if (tid == 0) H[d] = red[0] + red[1] + red[2] + red[3];
}

// ---------------------------------------------------------------------------
// Kernel F: logits
// ---------------------------------------------------------------------------
__global__ void logits_kernel(const float* __restrict__ H,
                              const float* __restrict__ We,
                              const float* __restrict__ be,
                              const float* __restrict__ Ws,
                              const float* __restrict__ bs,
                              float* __restrict__ outp)
{
    const int e = threadIdx.x;
    if (e < 9) {
        float acc = (e < 8) ? be[e] : bs[0];
        for (int d = 0; d < H1; ++d) {
            float wv = (e < 8) ? We[d * 8 + e] : Ws[d];
            acc = fmaf(H[d], wv, acc);
        }
        outp[e] = acc;
    }
}

// ---------------------------------------------------------------------------
extern "C" void kernel_launch(void* const* d_in, const int* in_sizes, int n_in,
                              void* d_out, int out_size, void* d_ws, size_t ws_size,
                              hipStream_t stream)
{
    const int* sentence   = (const int*)d_in[0];
    const int* syn_idx    = (const int*)d_in[1];
    const float* emb      = (const float*)d_in[2];
    const float* Wk_f     = (const float*)d_in[3];
    const float* Wr_f     = (const float*)d_in[4];
    const float* b_f      = (const float*)d_in[5];
    const float* Wk_b     = (const float*)d_in[6];
    const float* Wr_b     = (const float*)d_in[7];
    const float* b_b      = (const float*)d_in[8];
    const float* W1       = (const float*)d_in[9];
    const float* b1       = (const float*)d_in[10];
    const float* W2       = (const float*)d_in[11];
    const float* b2       = (const float*)d_in[12];
    const float* We       = (const float*)d_in[13];
    const float* be       = (const float*)d_in[14];
    const float* Ws       = (const float*)d_in[15];
    const float* bs       = (const float*)d_in[16];

    float* ws     = (float*)d_ws;
    float* Xf     = ws;                      // [2048,600]
    float* Xb     = Xf + (long)SEQ * G4;     // [2048,600]
    float* hidden = Xb + (long)SEQ * G4;     // [2048,300]
    float* outm   = hidden + (long)SEQ * H1; // [2048,300]
    float* whh    = outm + (long)SEQ * H1;   // [2048,300]
    float* H      = whh + (long)SEQ * H1;    // [300]

    float* outp = (float*)d_out;

    xpre_kernel<<<dim3(SEQ / 8, 2), 640, 0, stream>>>(sentence, emb, Wk_f, b_f, Wk_b, b_b, Xf, Xb);
    lstm_scan_kernel<<<2, 256, 0, stream>>>(Xf, Xb, Wr_f, Wr_b, hidden);
    w1_kernel<<<SEQ / 8, 320, 0, stream>>>(hidden, W1, b1, outm);
    attn_kernel<<<SEQ, 320, 0, stream>>>(sentence, syn_idx, emb, outm, hidden, W2, b2, whh);
    hred_kernel<<<H1, 256, 0, stream>>>(whh, H);
    logits_kernel<<<1, 64, 0, stream>>>(H, We, be, Ws, bs, outp);
}

// Round 6
// 2277.548 us; speedup vs baseline: 1.8373x; 1.0353x over previous
//
#include <hip/hip_runtime.h>
#include <hip/hip_bf16.h>

#define SEQ   2048
#define DIM   300
#define UU    150
#define G4    600   // 4*U
#define H1    300
#define NSYN  4

typedef _Float16 half2v __attribute__((ext_vector_type(2)));
union HU { unsigned u; half2v h; };

static __device__ __forceinline__ float sigm(float x) { return 1.0f / (1.0f + __expf(-x)); }
static __device__ __forceinline__ float tanh_fast(float x) { return 1.0f - 2.0f / (1.0f + __expf(2.0f * x)); }

// HW dot2: acc += w.x*h.x + w.y*h.y  (f16 pairs, f32 accumulate).
// h arrives in an SGPR (from v_readlane) — VOP3P allows one scalar source.
// R5 evidence: the __builtin_amdgcn_fdot2 path silently fell back to
// cvt+fma (~1200 instr/step == measured 2430 cyc/step); asm forces the issue.
static __device__ __forceinline__ float dot2acc(unsigned w, int h, float acc) {
    asm("v_dot2_f32_f16 %0, %1, %2, %0" : "+v"(acc) : "v"(w), "s"(h));
    return acc;
}

// LDS-only barrier: drains lgkmcnt (LDS) but NOT vmcnt.
#define LDS_BARRIER() asm volatile("s_waitcnt lgkmcnt(0)\n\ts_barrier" ::: "memory")

// ---------------------------------------------------------------------------
// Kernel A: emb = embedding[sentence];  Xpre_dir = emb @ Wk_dir + b_dir
// ---------------------------------------------------------------------------
__global__ void xpre_kernel(const int* __restrict__ sentence,
                            const float* __restrict__ emb_mat,
                            const float* __restrict__ Wk_f,
                            const float* __restrict__ b_f,
                            const float* __restrict__ Wk_b,
                            const float* __restrict__ b_b,
                            float* __restrict__ Xf, float* __restrict__ Xb)
{
    const int dir = blockIdx.y;
    const float* Wk = dir ? Wk_b : Wk_f;
    const float* bb = dir ? b_b : b_f;
    float* X = dir ? Xb : Xf;

    const int s0  = blockIdx.x * 8;
    const int tid = threadIdx.x;

    __shared__ int   sids[8];
    __shared__ float embs[8][DIM];

    if (tid < 8) sids[tid] = sentence[s0 + tid];
    __syncthreads();
    for (int e = tid; e < 8 * DIM; e += 640) {
        int r = e / DIM, d = e - r * DIM;
        embs[r][d] = emb_mat[(long)sids[r] * DIM + d];
    }
    __syncthreads();

    if (tid < G4) {
        float acc[8];
        float bv = bb[tid];
        #pragma unroll
        for (int r = 0; r < 8; ++r) acc[r] = bv;
        for (int k = 0; k < DIM; ++k) {
            float wv = Wk[k * G4 + tid];
            #pragma unroll
            for (int r = 0; r < 8; ++r) acc[r] = fmaf(embs[r][k], wv, acc[r]);
        }
        #pragma unroll
        for (int r = 0; r < 8; ++r) X[(long)(s0 + r) * G4 + tid] = acc[r];
    }
}

// ---------------------------------------------------------------------------
// Kernel B: LSTM scan. 2 blocks (one per direction), 256 threads.
// f16-packed weights in registers (225 regs), h broadcast via readlane->SGPR,
// HW v_dot2_f32_f16 accumulate, LDS-only barriers between phases.
// ---------------------------------------------------------------------------
#define REP75(F) \
  F(0) F(1) F(2) F(3) F(4) F(5) F(6) F(7) F(8) F(9) \
  F(10) F(11) F(12) F(13) F(14) F(15) F(16) F(17) F(18) F(19) \
  F(20) F(21) F(22) F(23) F(24) F(25) F(26) F(27) F(28) F(29) \
  F(30) F(31) F(32) F(33) F(34) F(35) F(36) F(37) F(38) F(39) \
  F(40) F(41) F(42) F(43) F(44) F(45) F(46) F(47) F(48) F(49) \
  F(50) F(51) F(52) F(53) F(54) F(55) F(56) F(57) F(58) F(59) \
  F(60) F(61) F(62) F(63) F(64) F(65) F(66) F(67) F(68) F(69) \
  F(70) F(71) F(72) F(73) F(74)

static __device__ __forceinline__ unsigned packpair(const float* __restrict__ Wr, int c, int k) {
    HU x;
    x.h.x = (_Float16)Wr[(2 * k) * G4 + c];
    x.h.y = (_Float16)Wr[(2 * k + 1) * G4 + c];
    return x.u;
}

__global__ __launch_bounds__(256) __attribute__((amdgpu_waves_per_eu(1, 1)))
void lstm_scan_kernel(
    const float* __restrict__ Xf, const float* __restrict__ Xb,
    const float* __restrict__ Wr_f, const float* __restrict__ Wr_b,
    float* __restrict__ hidden)
{
    const int dir = blockIdx.x;
    const float* X  = dir ? Xb : Xf;
    const float* Wr = dir ? Wr_b : Wr_f;
    const int tid  = threadIdx.x;
    const int lane = tid & 63;

    __shared__ float zs[G4];
    __shared__ __align__(4) _Float16 hs16[256];   // 128 packed pairs, zero-padded

    const int c0 = tid;
    const int c1 = tid + 256;
    const bool has2 = (tid < 88);
    const int c2 = has2 ? (tid + 512) : 599;

    // --- f16-packed weights in named registers ---
#define WDECL(k) unsigned wA_##k, wB_##k, wC_##k;
    REP75(WDECL)
#undef WDECL
#define WLOAD(k) wA_##k = packpair(Wr, c0, k); wB_##k = packpair(Wr, c1, k); wC_##k = packpair(Wr, c2, k);
    REP75(WLOAD)
#undef WLOAD

    if (tid < 128) ((unsigned*)hs16)[tid] = 0u;   // h = 0
    float c = 0.0f;

    int t = dir ? (SEQ - 1) : 0;
    const int dt = dir ? -1 : 1;
    float x0 = X[t * G4 + c0];
    float x1 = X[t * G4 + c1];
    float x2 = X[t * G4 + c2];
    __syncthreads();   // once, outside the loop: init visibility

    const unsigned* hp = (const unsigned*)hs16;

    for (int step = 0; step < SEQ; ++step) {
        const int tn = (step < SEQ - 1) ? (t + dt) : t;
        // prefetch next x (consumed next iteration; vmcnt wait overlaps dots)
        float xn0 = X[tn * G4 + c0];
        float xn1 = X[tn * G4 + c1];
        float xn2 = X[tn * G4 + c2];

        // lane-distributed h pairs (written by gate phase of previous step)
        unsigned hr0 = hp[lane];
        unsigned hr1 = hp[64 + lane];

        float a0 = x0, a1 = x1, a2 = x2;
#define DOT(k) { int hk = ((k) < 64) ? __builtin_amdgcn_readlane((int)hr0, (k)) \
                                     : __builtin_amdgcn_readlane((int)hr1, (k) - 64); \
                 a0 = dot2acc(wA_##k, hk, a0); \
                 a1 = dot2acc(wB_##k, hk, a1); \
                 a2 = dot2acc(wC_##k, hk, a2); }
        REP75(DOT)
#undef DOT

        zs[c0] = a0;
        zs[c1] = a1;
        if (has2) zs[c2] = a2;
        LDS_BARRIER();

        if (tid < UU) {
            float zi = zs[tid], zf = zs[UU + tid], zg = zs[2 * UU + tid], zo = zs[3 * UU + tid];
            float ig = sigm(zi);
            float fg = sigm(zf);
            float gg = tanh_fast(zg);
            float og = sigm(zo);
            c = fg * c + ig * gg;
            float hv = og * tanh_fast(c);
            hs16[tid] = (_Float16)hv;
            hidden[(long)t * H1 + dir * UU + tid] = hv;   // fire-and-forget
        }
        LDS_BARRIER();

        x0 = xn0; x1 = xn1; x2 = xn2;
        t = tn;
    }
}

// ---------------------------------------------------------------------------
// Kernel C: out = hidden @ W1 + b1   [2048,300]x[300,300]
// ---------------------------------------------------------------------------
__global__ void w1_kernel(const float* __restrict__ hidden,
                          const float* __restrict__ W1,
                          const float* __restrict__ b1,
                          float* __restrict__ outm)
{
    const int s0  = blockIdx.x * 8;
    const int tid = threadIdx.x;
    __shared__ float hl[8][H1];
    for (int e = tid; e < 8 * H1; e += 320)
        hl[e / H1][e - (e / H1) * H1] = hidden[(long)s0 * H1 + e];
    __syncthreads();

    if (tid < H1) {
        float acc[8];
        float bv = b1[tid];
        #pragma unroll
        for (int r = 0; r < 8; ++r) acc[r] = bv;
        for (int k = 0; k < H1; ++k) {
            float wv = W1[k * H1 + tid];
            #pragma unroll
            for (int r = 0; r < 8; ++r) acc[r] = fmaf(hl[r][k], wv, acc[r]);
        }
        #pragma unroll
        for (int r = 0; r < 8; ++r) outm[(long)(s0 + r) * H1 + tid] = acc[r];
    }
}

// ---------------------------------------------------------------------------
// Block reductions for 320-thread blocks (5 waves)
// ---------------------------------------------------------------------------
static __device__ __forceinline__ float4 blockReduce4(float4 v, float* red, int tid)
{
    #pragma unroll
    for (int off = 32; off > 0; off >>= 1) {
        v.x += __shfl_down(v.x, off);
        v.y += __shfl_down(v.y, off);
        v.z += __shfl_down(v.z, off);
        v.w += __shfl_down(v.w, off);
    }
    __syncthreads();
    if ((tid & 63) == 0) {
        int wv = tid >> 6;
        red[wv * 4 + 0] = v.x; red[wv * 4 + 1] = v.y;
        red[wv * 4 + 2] = v.z; red[wv * 4 + 3] = v.w;
    }
    __syncthreads();
    float4 r;
    r.x = red[0]; r.y = red[1]; r.z = red[2]; r.w = red[3];
    #pragma unroll
    for (int wv = 1; wv < 5; ++wv) {
        r.x += red[wv * 4 + 0]; r.y += red[wv * 4 + 1];
        r.z += red[wv * 4 + 2]; r.w += red[wv * 4 + 3];
    }
    return r;
}

static __device__ __forceinline__ float blockReduce1(float v, float* red, int tid)
{
    #pragma unroll
    for (int off = 32; off > 0; off >>= 1) v += __shfl_down(v, off);
    __syncthreads();
    if ((tid & 63) == 0) red[tid >> 6] = v;
    __syncthreads();
    return red[0] + red[1] + red[2] + red[3] + red[4];
}

// ---------------------------------------------------------------------------
// Kernel D: per-position synonym attention; whh[s][d] = c2[s]*h_hat[s][d]
// ---------------------------------------------------------------------------
__global__ void attn_kernel(const int* __restrict__ sentence,
                            const int* __restrict__ syn_idx,
                            const float* __restrict__ emb_mat,
                            const float* __restrict__ outm,
                            const float* __restrict__ hidden,
                            const float* __restrict__ W2,
                            const float* __restrict__ b2,
                            float* __restrict__ whh)
{
    const int s   = blockIdx.x;
    const int t   = s ? (s - 1) : 0;
    const int tid = threadIdx.x;
    __shared__ float red[20];

    const int sent = sentence[s];
    const long i0 = (long)syn_idx[sent * NSYN + 0] * DIM;
    const long i1 = (long)syn_idx[sent * NSYN + 1] * DIM;
    const long i2 = (long)syn_idx[sent * NSYN + 2] * DIM;
    const long i3 = (long)syn_idx[sent * NSYN + 3] * DIM;

    float se0 = 0.f, se1 = 0.f, se2 = 0.f, se3 = 0.f, od = 0.f, hd = 0.f;
    if (tid < DIM) {
        se0 = emb_mat[i0 + tid];
        se1 = emb_mat[i1 + tid];
        se2 = emb_mat[i2 + tid];
        se3 = emb_mat[i3 + tid];
        od  = outm[(long)t * H1 + tid];
        hd  = hidden[(long)t * H1 + tid];
    }

    float4 dots = blockReduce4(make_float4(se0 * od, se1 * od, se2 * od, se3 * od), red, tid);
    float c0 = __expf(dots.x), c1 = __expf(dots.y), c2c = __expf(dots.z), c3 = __expf(dots.w);

    float hh = fmaf(c0, se0, fmaf(c1, se1, fmaf(c2c, se2, fmaf(c3, se3, hd))));

    float w2v = (tid < DIM) ? W2[tid] : 0.f;
    float dot2 = blockReduce1(hh * w2v, red, tid);
    float cc = __expf(tanh_fast(dot2 + b2[0]));

    if (tid < DIM) whh[(long)s * H1 + tid] = cc * hh;
}

// ---------------------------------------------------------------------------
// Kernel E: H[d] = sum_s whh[s][d]
// ---------------------------------------------------------------------------
__global__ void hred_kernel(const float* __restrict__ whh, float* __restrict__ H)
{
    const int d   = blockIdx.x;
    const int tid = threadIdx.x;
    float acc = 0.f;
    for (int s = tid; s < SEQ; s += 256) acc += whh[(long)s * H1 + d];
    #pragma unroll
    for (int off = 32; off > 0; off >>= 1) acc += __shfl_down(acc, off);
    __shared__ float red[4];
    if ((tid & 63) == 0) red[tid >> 6] = acc;
    __syncthreads();
    if (tid == 0) H[d] = red[0] + red[1] + red[2] + red[3];
}

// ---------------------------------------------------------------------------
// Kernel F: logits
// ---------------------------------------------------------------------------
__global__ void logits_kernel(const float* __restrict__ H,
                              const float* __restrict__ We,
                              const float* __restrict__ be,
                              const float* __restrict__ Ws,
                              const float* __restrict__ bs,
                              float* __restrict__ outp)
{
    const int e = threadIdx.x;
    if (e < 9) {
        float acc = (e < 8) ? be[e] : bs[0];
        for (int d = 0; d < H1; ++d) {
            float wv = (e < 8) ? We[d * 8 + e] : Ws[d];
            acc = fmaf(H[d], wv, acc);
        }
        outp[e] = acc;
    }
}

// ---------------------------------------------------------------------------
extern "C" void kernel_launch(void* const* d_in, const int* in_sizes, int n_in,
                              void* d_out, int out_size, void* d_ws, size_t ws_size,
                              hipStream_t stream)
{
    const int* sentence   = (const int*)d_in[0];
    const int* syn_idx    = (const int*)d_in[1];
    const float* emb      = (const float*)d_in[2];
    const float* Wk_f     = (const float*)d_in[3];
    const float* Wr_f     = (const float*)d_in[4];
    const float* b_f      = (const float*)d_in[5];
    const float* Wk_b     = (const float*)d_in[6];
    const float* Wr_b     = (const float*)d_in[7];
    const float* b_b      = (const float*)d_in[8];
    const float* W1       = (const float*)d_in[9];
    const float* b1       = (const float*)d_in[10];
    const float* W2       = (const float*)d_in[11];
    const float* b2       = (const float*)d_in[12];
    const float* We       = (const float*)d_in[13];
    const float* be       = (const float*)d_in[14];
    const float* Ws       = (const float*)d_in[15];
    const float* bs       = (const float*)d_in[16];

    float* ws     = (float*)d_ws;
    float* Xf     = ws;                      // [2048,600]
    float* Xb     = Xf + (long)SEQ * G4;     // [2048,600]
    float* hidden = Xb + (long)SEQ * G4;     // [2048,300]
    float* outm   = hidden + (long)SEQ * H1; // [2048,300]
    float* whh    = outm + (long)SEQ * H1;   // [2048,300]
    float* H      = whh + (long)SEQ * H1;    // [300]

    float* outp = (float*)d_out;

    xpre_kernel<<<dim3(SEQ / 8, 2), 640, 0, stream>>>(sentence, emb, Wk_f, b_f, Wk_b, b_b, Xf, Xb);
    lstm_scan_kernel<<<2, 256, 0, stream>>>(Xf, Xb, Wr_f, Wr_b, hidden);
    w1_kernel<<<SEQ / 8, 320, 0, stream>>>(hidden, W1, b1, outm);
    attn_kernel<<<SEQ, 320, 0, stream>>>(sentence, syn_idx, emb, outm, hidden, W2, b2, whh);
    hred_kernel<<<H1, 256, 0, stream>>>(whh, H);
    logits_kernel<<<1, 64, 0, stream>>>(H, We, be, Ws, bs, outp);
}